// Round 2
// baseline (539.986 us; speedup 1.0000x reference)
//
#include <hip/hip_runtime.h>

// Attention: B=4, H=16, S=2048, D=64. Q,K,V,out = float32; mask = int32 (nonzero = masked).
// Flash-style: block = (b,h, 64 q-rows), 4 waves x 16 q-rows, 32-key steps.
// fp32 inputs converted to bf16 (RNE) at staging; MFMA 16x16x32 bf16, fp32 accum.
// Layouts (guide-verified, m89/m120):
//   A: lane holds A[m=lane&15][k=(lane>>4)*8+j], j=0..7
//   B: lane holds B[k=(lane>>4)*8+j][n=lane&15]
//   C/D: lane holds D[row=(lane>>4)*4+reg][col=lane&15]

#define SEQ 2048
#define DIM 64
#define NEG_SCALED -1.25e8f   // (-1e9)/sqrt(64)
#define LOG2E 1.44269504088896340736f

typedef short bf16x8 __attribute__((ext_vector_type(8)));
typedef float f32x4 __attribute__((ext_vector_type(4)));

static __device__ __forceinline__ unsigned short f2bf(float f) {
    unsigned int u = __float_as_uint(f);
    u += 0x7fffu + ((u >> 16) & 1u);   // RNE
    return (unsigned short)(u >> 16);
}

__global__ __launch_bounds__(256)
void attn_fwd_kernel(const float* __restrict__ Q,
                     const float* __restrict__ K,
                     const float* __restrict__ V,
                     const int* __restrict__ mask,
                     float* __restrict__ O)
{
    const int bh   = blockIdx.y;          // b*16 + h
    const int b    = bh >> 4;
    const int q0   = blockIdx.x * 64;
    const int tid  = threadIdx.x;
    const int wave = tid >> 6;
    const int lane = tid & 63;
    const int quad = lane >> 4;
    const int l16  = lane & 15;

    __shared__ __align__(16) unsigned short Klds[32][72];   // K[key][d], bf16
    __shared__ __align__(16) unsigned short VT[64][40];     // V^T[d][key], bf16
    __shared__ __align__(16) unsigned short Plds[4][16][40];

    const float* Qb = Q + (size_t)bh * SEQ * DIM;
    const float* Kb = K + (size_t)bh * SEQ * DIM;
    const float* Vb = V + (size_t)bh * SEQ * DIM;
    const int*   Mb = mask + (size_t)b * SEQ * SEQ;

    // Q fragments (A layout), converted fp32 -> bf16
    const int qrow_frag = q0 + wave * 16 + l16;
    bf16x8 qf0, qf1;
    {
        const float* qp = Qb + (size_t)qrow_frag * DIM + quad * 8;
        #pragma unroll
        for (int i = 0; i < 8; ++i) {
            qf0[i] = (short)f2bf(qp[i]);
            qf1[i] = (short)f2bf(qp[32 + i]);
        }
    }

    f32x4 acc[4];
    #pragma unroll
    for (int dg = 0; dg < 4; ++dg) acc[dg] = (f32x4){0.f, 0.f, 0.f, 0.f};
    float mrow[4] = {-INFINITY, -INFINITY, -INFINITY, -INFINITY};
    float lrow[4] = {0.f, 0.f, 0.f, 0.f};

    // staging assignments (256 threads, 8 fp32 elements each per tile)
    const int skey = tid >> 3;        // K: key 0..31
    const int sd0  = (tid & 7) * 8;
    const int vkey = tid & 31;        // V: key-major so transpose writes spread banks
    const int vd0  = (tid >> 5) * 8;

    const int qrow_m = q0 + wave * 16 + quad * 4;  // + reg -> mask/out row

    for (int kb = 0; kb < SEQ; kb += 32) {
        __syncthreads();
        // ---- stage K tile: fp32 -> bf16 ----
        {
            const float* kp = Kb + (size_t)(kb + skey) * DIM + sd0;
            union { uint4 u4; unsigned short s[8]; } kw;
            #pragma unroll
            for (int i = 0; i < 8; ++i) kw.s[i] = f2bf(kp[i]);
            *(uint4*)&Klds[skey][sd0] = kw.u4;
        }
        // ---- stage V tile transposed: fp32 -> bf16 ----
        {
            const float* vp = Vb + (size_t)(kb + vkey) * DIM + vd0;
            #pragma unroll
            for (int i = 0; i < 8; ++i) VT[vd0 + i][vkey] = f2bf(vp[i]);
        }
        __syncthreads();

        // ---- QK^T: S_tile 16q x 32k ----
        f32x4 sc[2];
        sc[0] = (f32x4){0.f, 0.f, 0.f, 0.f};
        sc[1] = (f32x4){0.f, 0.f, 0.f, 0.f};
        #pragma unroll
        for (int nt = 0; nt < 2; ++nt) {
            bf16x8 kf0 = *(const bf16x8*)&Klds[nt * 16 + l16][quad * 8];
            bf16x8 kf1 = *(const bf16x8*)&Klds[nt * 16 + l16][32 + quad * 8];
            sc[nt] = __builtin_amdgcn_mfma_f32_16x16x32_bf16(qf0, kf0, sc[nt], 0, 0, 0);
            sc[nt] = __builtin_amdgcn_mfma_f32_16x16x32_bf16(qf1, kf1, sc[nt], 0, 0, 0);
        }

        // ---- mask + scale ----
        float x[2][4];
        #pragma unroll
        for (int nt = 0; nt < 2; ++nt) {
            #pragma unroll
            for (int r = 0; r < 4; ++r) {
                int mv = Mb[(size_t)(qrow_m + r) * SEQ + kb + nt * 16 + l16];
                x[nt][r] = mv ? NEG_SCALED : sc[nt][r] * 0.125f;
            }
        }

        // ---- online softmax (rows live in 16-lane groups) ----
        float p[2][4];
        #pragma unroll
        for (int r = 0; r < 4; ++r) {
            float rm = fmaxf(x[0][r], x[1][r]);
            #pragma unroll
            for (int off = 1; off < 16; off <<= 1)
                rm = fmaxf(rm, __shfl_xor(rm, off, 16));
            float mn = fmaxf(mrow[r], rm);
            float alpha = exp2f((mrow[r] - mn) * LOG2E);
            mrow[r] = mn;
            float p0 = exp2f((x[0][r] - mn) * LOG2E);
            float p1 = exp2f((x[1][r] - mn) * LOG2E);
            p[0][r] = p0; p[1][r] = p1;
            float rs = p0 + p1;
            #pragma unroll
            for (int off = 1; off < 16; off <<= 1)
                rs += __shfl_xor(rs, off, 16);
            lrow[r] = lrow[r] * alpha + rs;
            #pragma unroll
            for (int dg = 0; dg < 4; ++dg)
                acc[dg][r] *= alpha;
        }

        // ---- P: C-layout -> LDS -> A-layout (per-wave buffer, no barrier) ----
        #pragma unroll
        for (int nt = 0; nt < 2; ++nt)
            #pragma unroll
            for (int r = 0; r < 4; ++r)
                Plds[wave][quad * 4 + r][nt * 16 + l16] = f2bf(p[nt][r]);

        bf16x8 pf = *(const bf16x8*)&Plds[wave][l16][quad * 8];

        // ---- PV: O_tile 16q x 64d ----
        #pragma unroll
        for (int dg = 0; dg < 4; ++dg) {
            bf16x8 vf = *(const bf16x8*)&VT[dg * 16 + l16][quad * 8];
            acc[dg] = __builtin_amdgcn_mfma_f32_16x16x32_bf16(pf, vf, acc[dg], 0, 0, 0);
        }
    }

    // ---- epilogue: normalize and store fp32 ----
    float* Ob = O + (size_t)bh * SEQ * DIM;
    #pragma unroll
    for (int r = 0; r < 4; ++r) {
        float inv = 1.f / lrow[r];
        #pragma unroll
        for (int dg = 0; dg < 4; ++dg)
            Ob[(size_t)(qrow_m + r) * DIM + dg * 16 + l16] = acc[dg][r] * inv;
    }
}

extern "C" void kernel_launch(void* const* d_in, const int* in_sizes, int n_in,
                              void* d_out, int out_size, void* d_ws, size_t ws_size,
                              hipStream_t stream) {
    const float* Q = (const float*)d_in[0];
    const float* K = (const float*)d_in[1];
    const float* V = (const float*)d_in[2];
    const int* mask = (const int*)d_in[3];
    float*        O = (float*)d_out;

    dim3 grid(SEQ / 64, 4 * 16);   // (q-tiles, B*H)
    attn_fwd_kernel<<<grid, 256, 0, stream>>>(Q, K, V, mask, O);
}